// Round 10
// baseline (48.853 us; speedup 1.0000x reference)
//
#include <hip/hip_runtime.h>

#define C 128
#define CRED 32
#define K 7
#define KK 49
#define H 56
#define W 56
#define P (H*W)        // 3136
#define B 8
#define NPIX (B*P)     // 25088
#define BN_EPS 1e-5

// ---------------- fast-path ws layout (floats) ----------------
#define T_OFF 0
#define T_SIZE (B*CRED*P)                 // 802816
#define KERN_OFF (T_OFF + T_SIZE)
#define KERN_SIZE (B*KK*P)                // 1229312
#define NBLK_A (49*B)                     // 392
#define PSUM_OFF (KERN_OFF + KERN_SIZE)
#define PSQ_OFF (PSUM_OFF + NBLK_A*CRED)
#define SS_OFF  (PSQ_OFF + NBLK_A*CRED)
#define SCALE_OFF SS_OFF
#define SHIFT_OFF (SS_OFF + CRED)
#define WS_NEED ((size_t)(SHIFT_OFF + CRED) * sizeof(float))

// fallback layout
#define FB_SCALE_OFF T_SIZE
#define FB_SHIFT_OFF (T_SIZE + CRED)

// ============ kA v3: t = w1*x + b1 + BN partials. No LDS; w1 via uniform scalar loads ============
__global__ __launch_bounds__(256) void kA_conv1(const float* __restrict__ x,
                                                const float* __restrict__ w1,
                                                const float* __restrict__ b1,
                                                float* __restrict__ ws) {
    int tid = threadIdx.x;
    int bx = blockIdx.x;
    int b  = blockIdx.y;
    int px = tid & 63;
    int p  = bx * 64 + px;                       // < P (49*64 == P)
    int ru8 = __builtin_amdgcn_readfirstlane((tid >> 6) * 8);   // wave-uniform r base
    const float* __restrict__ wq = w1 + (size_t)ru8 * C;        // uniform -> s_load
    const float* xb = x + (size_t)b * C * P + p;

    float acc[8];
#pragma unroll
    for (int u = 0; u < 8; ++u) acc[u] = 0.f;
#pragma unroll 8
    for (int c = 0; c < C; ++c) {
        float xv = xb[(size_t)c * P];
#pragma unroll
        for (int u = 0; u < 8; ++u)
            acc[u] = fmaf(wq[u * C + c], xv, acc[u]);
    }
#pragma unroll
    for (int u = 0; u < 8; ++u) acc[u] += b1[ru8 + u];

    float* tb = ws + T_OFF + (size_t)b * CRED * P + p;
#pragma unroll
    for (int u = 0; u < 8; ++u)
        tb[(size_t)(ru8 + u) * P] = acc[u];

    float s[8], q[8];
#pragma unroll
    for (int u = 0; u < 8; ++u) { s[u] = acc[u]; q[u] = acc[u] * acc[u]; }
#pragma unroll
    for (int off = 32; off; off >>= 1) {
#pragma unroll
        for (int u = 0; u < 8; ++u) {
            s[u] += __shfl_xor(s[u], off);
            q[u] += __shfl_xor(q[u], off);
        }
    }
    if (px == 0) {
        int blk = b * 49 + bx;
        float* psum = ws + PSUM_OFF + (size_t)blk * CRED + ru8;
        float* psq  = ws + PSQ_OFF  + (size_t)blk * CRED + ru8;
#pragma unroll
        for (int u = 0; u < 8; ++u) { psum[u] = s[u]; psq[u] = q[u]; }
    }
}

// ============ kB: finalize BN stats -> scale/shift (1 block, deterministic) ============
__global__ __launch_bounds__(256) void kB_bnfin(const float* __restrict__ gamma,
                                                const float* __restrict__ beta,
                                                float* __restrict__ ws) {
    __shared__ double sd1[8][CRED];
    __shared__ double sd2[8][CRED];
    int tid = threadIdx.x;
    int r = tid & 31, g = tid >> 5;
    double s1 = 0.0, s2 = 0.0;
    for (int i = g * 49; i < g * 49 + 49; ++i) {
        s1 += (double)ws[PSUM_OFF + i * CRED + r];
        s2 += (double)ws[PSQ_OFF + i * CRED + r];
    }
    sd1[g][r] = s1; sd2[g][r] = s2;
    __syncthreads();
    if (tid < CRED) {
        double S1 = 0.0, S2 = 0.0;
        for (int gg = 0; gg < 8; ++gg) { S1 += sd1[gg][tid]; S2 += sd2[gg][tid]; }
        double mean = S1 / NPIX;
        double var = S2 / NPIX - mean * mean;
        double sc = (double)gamma[tid] / sqrt(var + BN_EPS);
        ws[SCALE_OFF + tid] = (float)sc;
        ws[SHIFT_OFF + tid] = (float)((double)beta[tid] - mean * sc);
    }
}

// ============ kC v2: kern[b,k,h,w] = b2 + w2 * relu(t*scale+shift); float4 s_t reads ============
__global__ __launch_bounds__(256) void kC_kern(const float* __restrict__ w2,
                                               const float* __restrict__ b2,
                                               float* __restrict__ ws) {
    __shared__ float s_t[CRED * W];        // 32x56
    __shared__ float s_w2[KK * 33];        // padded: [k][33] kills dk-bank-conflict
    int tid = threadIdx.x;
    int h = blockIdx.x, b = blockIdx.y;
    for (int i = tid; i < KK * CRED; i += 256) {
        int k = i >> 5, r = i & 31;
        s_w2[k * 33 + r] = w2[i];
    }
    const float* scale = ws + SCALE_OFF;
    const float* shift = ws + SHIFT_OFF;
    for (int i = tid; i < CRED * W; i += 256) {
        int r = i / W, w = i - r * W;
        float v = ws[T_OFF + ((size_t)b * CRED + r) * P + h * W + w];
        v = fmaf(v, scale[r], shift[r]);
        s_t[r * W + w] = fmaxf(v, 0.f);
    }
    __syncthreads();
    for (int i = tid; i < KK * 14; i += 256) {   // 686 (k, w-quad) tasks
        int k = i / 14, w0 = (i - k * 14) * 4;
        float bb = b2[k];
        float a0 = bb, a1 = bb, a2 = bb, a3 = bb;
#pragma unroll
        for (int r = 0; r < CRED; ++r) {
            float4 tv = *(const float4*)&s_t[r * W + w0];
            float wv = s_w2[k * 33 + r];
            a0 = fmaf(wv, tv.x, a0);
            a1 = fmaf(wv, tv.y, a1);
            a2 = fmaf(wv, tv.z, a2);
            a3 = fmaf(wv, tv.w, a3);
        }
        float4 o = {a0, a1, a2, a3};
        *(float4*)&ws[KERN_OFF + ((size_t)b * KK + k) * P + h * W + w0] = o;
    }
}

// ============ kD2: tap-outer involution — NO per-thread kern array, spill-proof ============
// grid (56, 4): bx = b*7 + ht (8-row tile), by = z (32-ch chunk). block 448 = 8x56 px.
// All 8 float4 channel-groups staged in LDS upfront ([row][g][col] layout, 122KB),
// one sync, then 49 taps: kv loaded per tap from kern (single-use -> can't be
// hoisted into a 49-reg array) applied to acc[8] (32 VGPRs, static index).
#define TH 8
#define XROWS 14          // TH + 6
#define XPITCH 68
__global__ __launch_bounds__(448) void kD2_inv(const float* __restrict__ x,
                                               const float* __restrict__ ws,
                                               float* __restrict__ out) {
    __shared__ float4 s_x[XROWS * 8 * XPITCH];   // 14*8*68*16 = 121856 B
    int tid = threadIdx.x;
    int bx = blockIdx.x;
    int z  = blockIdx.y;
    int b = bx / 7, ht = bx - b * 7;
    int h0 = ht * TH;                     // 0..48
    int orow = tid / W;                   // 0..7
    int ocol = tid - orow * W;            // 0..55

    // staging geometry: 2 slots/thread, rows row0 and row0+7 (448*2 == 14*64)
    int row0 = tid >> 6, col0 = tid & 63;         // row0 0..6
    int hh0 = h0 - 3 + row0, ww0 = col0 - 3;
    float m0 = ((unsigned)hh0 < H && (unsigned)ww0 < W) ? 1.f : 0.f;
    int off0 = (m0 != 0.f) ? (hh0 * W + ww0) : 0;
    int hh1 = hh0 + 7;
    float m1 = ((unsigned)hh1 < H && (unsigned)ww0 < W) ? 1.f : 0.f;
    int off1 = (m1 != 0.f) ? (hh1 * W + ww0) : 0;
    int slot0b = (row0 * 8) * XPITCH + col0;          // + g*XPITCH
    int slot1b = ((row0 + 7) * 8) * XPITCH + col0;    // + g*XPITCH

    int cg0 = z * 32;
    const size_t xbase = ((size_t)b * C + cg0) * P;

    // stage all 8 groups (4 channels each); no syncs in between
#pragma unroll
    for (int g = 0; g < 8; ++g) {
        const float* xc = x + xbase + (size_t)(4 * g) * P;
        float4 f0, f1;
        f0.x = xc[off0] * m0;          f0.y = xc[P + off0] * m0;
        f0.z = xc[2 * P + off0] * m0;  f0.w = xc[3 * P + off0] * m0;
        f1.x = xc[off1] * m1;          f1.y = xc[P + off1] * m1;
        f1.z = xc[2 * P + off1] * m1;  f1.w = xc[3 * P + off1] * m1;
        s_x[slot0b + g * XPITCH] = f0;
        s_x[slot1b + g * XPITCH] = f1;
    }
    __syncthreads();

    int p0 = h0 * W + tid;                              // this thread's pixel
    const float* kp = ws + KERN_OFF + (size_t)b * KK * P + p0;

    float4 acc[8];
#pragma unroll
    for (int g = 0; g < 8; ++g) acc[g] = make_float4(0.f, 0.f, 0.f, 0.f);

    const float4* xs = s_x + orow * (8 * XPITCH) + ocol;
    for (int i = 0; i < K; ++i) {
        const float4* xr = xs + i * (8 * XPITCH);
#pragma unroll
        for (int j = 0; j < K; ++j) {
            float kv = kp[(size_t)(i * 7 + j) * P];     // coalesced, single-use
#pragma unroll
            for (int g = 0; g < 8; ++g) {
                float4 xv = xr[g * XPITCH + j];
                acc[g].x = fmaf(kv, xv.x, acc[g].x);
                acc[g].y = fmaf(kv, xv.y, acc[g].y);
                acc[g].z = fmaf(kv, xv.z, acc[g].z);
                acc[g].w = fmaf(kv, xv.w, acc[g].w);
            }
        }
    }

#pragma unroll
    for (int g = 0; g < 8; ++g) {
        float* ob = out + xbase + (size_t)(4 * g) * P + p0;
        ob[0]     = acc[g].x;
        ob[P]     = acc[g].y;
        ob[2 * P] = acc[g].z;
        ob[3 * P] = acc[g].w;
    }
}

// ===================== fallback (proven, needs only 3.3MB ws) =====================
__global__ __launch_bounds__(256) void k1_conv1(const float* __restrict__ x,
                                                const float* __restrict__ w1,
                                                const float* __restrict__ b1,
                                                float* __restrict__ t) {
    __shared__ float s_w1t[C * CRED];
    int tid = threadIdx.x;
    for (int i = tid; i < C * CRED; i += 256) {
        int c = i >> 5, r = i & 31;
        s_w1t[i] = w1[r * C + c];
    }
    __syncthreads();
    int b = blockIdx.y;
    int p = blockIdx.x * 256 + tid;
    if (p >= P) return;
    float acc[CRED];
#pragma unroll
    for (int r = 0; r < CRED; ++r) acc[r] = 0.f;
    const float* xb = x + (size_t)b * C * P + p;
    for (int c = 0; c < C; ++c) {
        float xv = xb[(size_t)c * P];
#pragma unroll
        for (int r = 0; r < CRED; ++r)
            acc[r] = fmaf(s_w1t[c * CRED + r], xv, acc[r]);
    }
    float* tb = t + (size_t)b * CRED * P + p;
#pragma unroll
    for (int r = 0; r < CRED; ++r)
        tb[(size_t)r * P] = acc[r] + b1[r];
}

__global__ __launch_bounds__(256) void k2_bnstats(const float* __restrict__ t,
                                                  const float* __restrict__ gamma,
                                                  const float* __restrict__ beta,
                                                  float* __restrict__ scale,
                                                  float* __restrict__ shift) {
    int r = blockIdx.x;
    int tid = threadIdx.x;
    double s = 0.0, s2 = 0.0;
    for (int i = tid; i < NPIX; i += 256) {
        int b = i / P, p = i - b * P;
        float v = t[((size_t)b * CRED + r) * P + p];
        s += v;
        s2 += (double)v * v;
    }
    __shared__ double ls[256], ls2[256];
    ls[tid] = s; ls2[tid] = s2;
    __syncthreads();
    for (int off = 128; off > 0; off >>= 1) {
        if (tid < off) { ls[tid] += ls[tid + off]; ls2[tid] += ls2[tid + off]; }
        __syncthreads();
    }
    if (tid == 0) {
        double mean = ls[0] / NPIX;
        double var = ls2[0] / NPIX - mean * mean;
        double sc = (double)gamma[r] / sqrt(var + BN_EPS);
        scale[r] = (float)sc;
        shift[r] = (float)((double)beta[r] - mean * sc);
    }
}

__global__ __launch_bounds__(256) void k3_involution(const float* __restrict__ x,
                                                     const float* __restrict__ t,
                                                     const float* __restrict__ scale,
                                                     const float* __restrict__ shift,
                                                     const float* __restrict__ w2,
                                                     const float* __restrict__ b2,
                                                     float* __restrict__ out) {
    int h = blockIdx.x;
    int b = blockIdx.y;
    int z = blockIdx.z;
    int tid = threadIdx.x;
    __shared__ float s_w2[KK * CRED];
    __shared__ float s_t[CRED * W];
    __shared__ float s_kern[KK][W];
    __shared__ float s_x[4][K][64];
    for (int i = tid; i < KK * CRED; i += 256) s_w2[i] = w2[i];
    for (int i = tid; i < CRED * W; i += 256) {
        int r = i / W, w = i - r * W;
        float v = t[((size_t)b * CRED + r) * P + h * W + w];
        v = fmaf(v, scale[r], shift[r]);
        s_t[r * W + w] = fmaxf(v, 0.f);
    }
    __syncthreads();
    for (int i = tid; i < KK * W; i += 256) {
        int k = i / W, w = i - k * W;
        float acc = b2[k];
#pragma unroll
        for (int r = 0; r < CRED; ++r)
            acc = fmaf(s_w2[k * CRED + r], s_t[r * W + w], acc);
        s_kern[k][w] = acc;
    }
    __syncthreads();
    int w = tid % W;
    int c4 = tid / W;
    float kr[KK];
#pragma unroll
    for (int k = 0; k < KK; ++k) kr[k] = s_kern[k][w];
    int cbase = z * (C / 2);
    for (int cg = cbase; cg < cbase + C / 2; cg += 4) {
        for (int i = tid; i < 4 * K * 64; i += 256) {
            int col = i & 63;
            int rc = i >> 6;
            int cc = rc / K;
            int row = rc - cc * K;
            int hh = h - 3 + row;
            int ww = col - 3;
            float v = 0.f;
            if ((unsigned)hh < H && (unsigned)ww < W)
                v = x[(((size_t)b * C + cg + cc) * H + hh) * W + ww];
            s_x[cc][row][col] = v;
        }
        __syncthreads();
        if (tid < 4 * W) {
            float acc = 0.f;
#pragma unroll
            for (int i = 0; i < K; ++i)
#pragma unroll
                for (int j = 0; j < K; ++j)
                    acc = fmaf(kr[i * K + j], s_x[c4][i][w + j], acc);
            out[(((size_t)b * C + cg + c4) * H + h) * W + w] = acc;
        }
        __syncthreads();
    }
}

extern "C" void kernel_launch(void* const* d_in, const int* in_sizes, int n_in,
                              void* d_out, int out_size, void* d_ws, size_t ws_size,
                              hipStream_t stream) {
    const float* x     = (const float*)d_in[0];
    const float* w1    = (const float*)d_in[1];
    const float* b1    = (const float*)d_in[2];
    const float* gamma = (const float*)d_in[3];
    const float* beta  = (const float*)d_in[4];
    const float* w2    = (const float*)d_in[5];
    const float* b2    = (const float*)d_in[6];
    float* out = (float*)d_out;
    float* ws  = (float*)d_ws;

    if (ws_size >= WS_NEED) {
        dim3 gA(49, B);
        kA_conv1<<<gA, 256, 0, stream>>>(x, w1, b1, ws);
        kB_bnfin<<<1, 256, 0, stream>>>(gamma, beta, ws);
        dim3 gC(H, B);
        kC_kern<<<gC, 256, 0, stream>>>(w2, b2, ws);
        dim3 gD(7 * B, 4);
        kD2_inv<<<gD, 448, 0, stream>>>(x, ws, out);
    } else {
        float* t     = ws;
        float* scale = ws + FB_SCALE_OFF;
        float* shift = ws + FB_SHIFT_OFF;
        dim3 g1((P + 255) / 256, B);
        k1_conv1<<<g1, 256, 0, stream>>>(x, w1, b1, t);
        k2_bnstats<<<CRED, 256, 0, stream>>>(t, gamma, beta, scale, shift);
        dim3 g3(H, B, 2);
        k3_involution<<<g3, 256, 0, stream>>>(x, t, scale, shift, w2, b2, out);
    }
}

// Round 11
// 47.645 us; speedup vs baseline: 1.0254x; 1.0254x over previous
//
#include <hip/hip_runtime.h>

#define C 128
#define CRED 32
#define K 7
#define KK 49
#define H 56
#define W 56
#define P (H*W)        // 3136
#define B 8
#define NPIX (B*P)     // 25088
#define BN_EPS 1e-5

// ---------------- fast-path ws layout (floats) ----------------
#define T_OFF 0
#define T_SIZE (B*CRED*P)                 // 802816
#define KERN_OFF (T_OFF + T_SIZE)
#define KERN_SIZE (B*KK*P)                // 1229312
#define NBLK_A (49*B)                     // 392
#define PSUM_OFF (KERN_OFF + KERN_SIZE)
#define PSQ_OFF (PSUM_OFF + NBLK_A*CRED)
#define SS_OFF  (PSQ_OFF + NBLK_A*CRED)
#define SCALE_OFF SS_OFF
#define SHIFT_OFF (SS_OFF + CRED)
#define WS_NEED ((size_t)(SHIFT_OFF + CRED) * sizeof(float))

// fallback layout
#define FB_SCALE_OFF T_SIZE
#define FB_SHIFT_OFF (T_SIZE + CRED)

// ============ kA v3: t = w1*x + b1 + BN partials. No LDS; w1 via uniform scalar loads ============
__global__ __launch_bounds__(256) void kA_conv1(const float* __restrict__ x,
                                                const float* __restrict__ w1,
                                                const float* __restrict__ b1,
                                                float* __restrict__ ws) {
    int tid = threadIdx.x;
    int bx = blockIdx.x;
    int b  = blockIdx.y;
    int px = tid & 63;
    int p  = bx * 64 + px;                       // < P (49*64 == P)
    int ru8 = __builtin_amdgcn_readfirstlane((tid >> 6) * 8);   // wave-uniform r base
    const float* __restrict__ wq = w1 + (size_t)ru8 * C;        // uniform -> s_load
    const float* xb = x + (size_t)b * C * P + p;

    float acc[8];
#pragma unroll
    for (int u = 0; u < 8; ++u) acc[u] = 0.f;
#pragma unroll 8
    for (int c = 0; c < C; ++c) {
        float xv = xb[(size_t)c * P];
#pragma unroll
        for (int u = 0; u < 8; ++u)
            acc[u] = fmaf(wq[u * C + c], xv, acc[u]);
    }
#pragma unroll
    for (int u = 0; u < 8; ++u) acc[u] += b1[ru8 + u];

    float* tb = ws + T_OFF + (size_t)b * CRED * P + p;
#pragma unroll
    for (int u = 0; u < 8; ++u)
        tb[(size_t)(ru8 + u) * P] = acc[u];

    float s[8], q[8];
#pragma unroll
    for (int u = 0; u < 8; ++u) { s[u] = acc[u]; q[u] = acc[u] * acc[u]; }
#pragma unroll
    for (int off = 32; off; off >>= 1) {
#pragma unroll
        for (int u = 0; u < 8; ++u) {
            s[u] += __shfl_xor(s[u], off);
            q[u] += __shfl_xor(q[u], off);
        }
    }
    if (px == 0) {
        int blk = b * 49 + bx;
        float* psum = ws + PSUM_OFF + (size_t)blk * CRED + ru8;
        float* psq  = ws + PSQ_OFF  + (size_t)blk * CRED + ru8;
#pragma unroll
        for (int u = 0; u < 8; ++u) { psum[u] = s[u]; psq[u] = q[u]; }
    }
}

// ============ kB: finalize BN stats -> scale/shift (1 block, deterministic) ============
__global__ __launch_bounds__(256) void kB_bnfin(const float* __restrict__ gamma,
                                                const float* __restrict__ beta,
                                                float* __restrict__ ws) {
    __shared__ double sd1[8][CRED];
    __shared__ double sd2[8][CRED];
    int tid = threadIdx.x;
    int r = tid & 31, g = tid >> 5;
    double s1 = 0.0, s2 = 0.0;
    for (int i = g * 49; i < g * 49 + 49; ++i) {
        s1 += (double)ws[PSUM_OFF + i * CRED + r];
        s2 += (double)ws[PSQ_OFF + i * CRED + r];
    }
    sd1[g][r] = s1; sd2[g][r] = s2;
    __syncthreads();
    if (tid < CRED) {
        double S1 = 0.0, S2 = 0.0;
        for (int gg = 0; gg < 8; ++gg) { S1 += sd1[gg][tid]; S2 += sd2[gg][tid]; }
        double mean = S1 / NPIX;
        double var = S2 / NPIX - mean * mean;
        double sc = (double)gamma[tid] / sqrt(var + BN_EPS);
        ws[SCALE_OFF + tid] = (float)sc;
        ws[SHIFT_OFF + tid] = (float)((double)beta[tid] - mean * sc);
    }
}

// ============ kC v2: kern[b,k,h,w] = b2 + w2 * relu(t*scale+shift); float4 s_t reads ============
__global__ __launch_bounds__(256) void kC_kern(const float* __restrict__ w2,
                                               const float* __restrict__ b2,
                                               float* __restrict__ ws) {
    __shared__ float s_t[CRED * W];        // 32x56
    __shared__ float s_w2[KK * 33];        // padded: [k][33] kills dk-bank-conflict
    int tid = threadIdx.x;
    int h = blockIdx.x, b = blockIdx.y;
    for (int i = tid; i < KK * CRED; i += 256) {
        int k = i >> 5, r = i & 31;
        s_w2[k * 33 + r] = w2[i];
    }
    const float* scale = ws + SCALE_OFF;
    const float* shift = ws + SHIFT_OFF;
    for (int i = tid; i < CRED * W; i += 256) {
        int r = i / W, w = i - r * W;
        float v = ws[T_OFF + ((size_t)b * CRED + r) * P + h * W + w];
        v = fmaf(v, scale[r], shift[r]);
        s_t[r * W + w] = fmaxf(v, 0.f);
    }
    __syncthreads();
    for (int i = tid; i < KK * 14; i += 256) {   // 686 (k, w-quad) tasks
        int k = i / 14, w0 = (i - k * 14) * 4;
        float bb = b2[k];
        float a0 = bb, a1 = bb, a2 = bb, a3 = bb;
#pragma unroll
        for (int r = 0; r < CRED; ++r) {
            float4 tv = *(const float4*)&s_t[r * W + w0];
            float wv = s_w2[k * 33 + r];
            a0 = fmaf(wv, tv.x, a0);
            a1 = fmaf(wv, tv.y, a1);
            a2 = fmaf(wv, tv.z, a2);
            a3 = fmaf(wv, tv.w, a3);
        }
        float4 o = {a0, a1, a2, a3};
        *(float4*)&ws[KERN_OFF + ((size_t)b * KK + k) * P + h * W + w0] = o;
    }
}

// ============ kD3: tap-outer involution, SMALL LDS (61KB -> 2 blocks/CU, 14 waves) ============
// grid (56, 8): bx = b*7 + ht (8-row tile), by = z (16-ch chunk = 4 float4 groups).
// block 448 = 8x56 px. acc[4] = 16 VGPR. #pragma unroll 1 on the tap-row loop keeps
// only 7 kv loads in the scheduling window -> allocator can't rebuild a 49-reg kern
// array (the round-5..10 spill trap).
#define TH 8
#define XROWS 14          // TH + 6
#define XPITCH 68
#define NG 4              // float4 channel groups per block
__global__ __launch_bounds__(448) void kD3_inv(const float* __restrict__ x,
                                               const float* __restrict__ ws,
                                               float* __restrict__ out) {
    __shared__ float4 s_x[XROWS * NG * XPITCH];   // 14*4*68*16 = 60928 B
    int tid = threadIdx.x;
    int bx = blockIdx.x;
    int z  = blockIdx.y;
    int b = bx / 7, ht = bx - b * 7;
    int h0 = ht * TH;                     // 0..48
    int orow = tid / W;                   // 0..7
    int ocol = tid - orow * W;            // 0..55

    // staging geometry: 2 slots/thread, rows row0 and row0+7 (448*2 == 14*64)
    int row0 = tid >> 6, col0 = tid & 63;         // row0 0..6
    int hh0 = h0 - 3 + row0, ww0 = col0 - 3;
    float m0 = ((unsigned)hh0 < H && (unsigned)ww0 < W) ? 1.f : 0.f;
    int off0 = (m0 != 0.f) ? (hh0 * W + ww0) : 0;
    int hh1 = hh0 + 7;
    float m1 = ((unsigned)hh1 < H && (unsigned)ww0 < W) ? 1.f : 0.f;
    int off1 = (m1 != 0.f) ? (hh1 * W + ww0) : 0;
    int slot0b = (row0 * NG) * XPITCH + col0;          // + g*XPITCH
    int slot1b = ((row0 + 7) * NG) * XPITCH + col0;    // + g*XPITCH

    int cg0 = z * 16;
    const size_t xbase = ((size_t)b * C + cg0) * P;

    // stage 4 groups (16 channels); no syncs in between
#pragma unroll
    for (int g = 0; g < NG; ++g) {
        const float* xc = x + xbase + (size_t)(4 * g) * P;
        float4 f0, f1;
        f0.x = xc[off0] * m0;          f0.y = xc[P + off0] * m0;
        f0.z = xc[2 * P + off0] * m0;  f0.w = xc[3 * P + off0] * m0;
        f1.x = xc[off1] * m1;          f1.y = xc[P + off1] * m1;
        f1.z = xc[2 * P + off1] * m1;  f1.w = xc[3 * P + off1] * m1;
        s_x[slot0b + g * XPITCH] = f0;
        s_x[slot1b + g * XPITCH] = f1;
    }
    __syncthreads();

    int p0 = h0 * W + tid;                              // this thread's pixel
    const float* kp = ws + KERN_OFF + (size_t)b * KK * P + p0;

    float4 acc[NG];
#pragma unroll
    for (int g = 0; g < NG; ++g) acc[g] = make_float4(0.f, 0.f, 0.f, 0.f);

    const float4* xs = s_x + orow * (NG * XPITCH) + ocol;
#pragma unroll 1
    for (int i = 0; i < K; ++i) {
        const float4* xr = xs + i * (NG * XPITCH);
#pragma unroll
        for (int j = 0; j < K; ++j) {
            float kv = kp[(size_t)(i * 7 + j) * P];     // coalesced, single-use
#pragma unroll
            for (int g = 0; g < NG; ++g) {
                float4 xv = xr[g * XPITCH + j];
                acc[g].x = fmaf(kv, xv.x, acc[g].x);
                acc[g].y = fmaf(kv, xv.y, acc[g].y);
                acc[g].z = fmaf(kv, xv.z, acc[g].z);
                acc[g].w = fmaf(kv, xv.w, acc[g].w);
            }
        }
    }

#pragma unroll
    for (int g = 0; g < NG; ++g) {
        float* ob = out + xbase + (size_t)(4 * g) * P + p0;
        ob[0]     = acc[g].x;
        ob[P]     = acc[g].y;
        ob[2 * P] = acc[g].z;
        ob[3 * P] = acc[g].w;
    }
}

// ===================== fallback (proven, needs only 3.3MB ws) =====================
__global__ __launch_bounds__(256) void k1_conv1(const float* __restrict__ x,
                                                const float* __restrict__ w1,
                                                const float* __restrict__ b1,
                                                float* __restrict__ t) {
    __shared__ float s_w1t[C * CRED];
    int tid = threadIdx.x;
    for (int i = tid; i < C * CRED; i += 256) {
        int c = i >> 5, r = i & 31;
        s_w1t[i] = w1[r * C + c];
    }
    __syncthreads();
    int b = blockIdx.y;
    int p = blockIdx.x * 256 + tid;
    if (p >= P) return;
    float acc[CRED];
#pragma unroll
    for (int r = 0; r < CRED; ++r) acc[r] = 0.f;
    const float* xb = x + (size_t)b * C * P + p;
    for (int c = 0; c < C; ++c) {
        float xv = xb[(size_t)c * P];
#pragma unroll
        for (int r = 0; r < CRED; ++r)
            acc[r] = fmaf(s_w1t[c * CRED + r], xv, acc[r]);
    }
    float* tb = t + (size_t)b * CRED * P + p;
#pragma unroll
    for (int r = 0; r < CRED; ++r)
        tb[(size_t)r * P] = acc[r] + b1[r];
}

__global__ __launch_bounds__(256) void k2_bnstats(const float* __restrict__ t,
                                                  const float* __restrict__ gamma,
                                                  const float* __restrict__ beta,
                                                  float* __restrict__ scale,
                                                  float* __restrict__ shift) {
    int r = blockIdx.x;
    int tid = threadIdx.x;
    double s = 0.0, s2 = 0.0;
    for (int i = tid; i < NPIX; i += 256) {
        int b = i / P, p = i - b * P;
        float v = t[((size_t)b * CRED + r) * P + p];
        s += v;
        s2 += (double)v * v;
    }
    __shared__ double ls[256], ls2[256];
    ls[tid] = s; ls2[tid] = s2;
    __syncthreads();
    for (int off = 128; off > 0; off >>= 1) {
        if (tid < off) { ls[tid] += ls[tid + off]; ls2[tid] += ls2[tid + off]; }
        __syncthreads();
    }
    if (tid == 0) {
        double mean = ls[0] / NPIX;
        double var = ls2[0] / NPIX - mean * mean;
        double sc = (double)gamma[r] / sqrt(var + BN_EPS);
        scale[r] = (float)sc;
        shift[r] = (float)((double)beta[r] - mean * sc);
    }
}

__global__ __launch_bounds__(256) void k3_involution(const float* __restrict__ x,
                                                     const float* __restrict__ t,
                                                     const float* __restrict__ scale,
                                                     const float* __restrict__ shift,
                                                     const float* __restrict__ w2,
                                                     const float* __restrict__ b2,
                                                     float* __restrict__ out) {
    int h = blockIdx.x;
    int b = blockIdx.y;
    int z = blockIdx.z;
    int tid = threadIdx.x;
    __shared__ float s_w2[KK * CRED];
    __shared__ float s_t[CRED * W];
    __shared__ float s_kern[KK][W];
    __shared__ float s_x[4][K][64];
    for (int i = tid; i < KK * CRED; i += 256) s_w2[i] = w2[i];
    for (int i = tid; i < CRED * W; i += 256) {
        int r = i / W, w = i - r * W;
        float v = t[((size_t)b * CRED + r) * P + h * W + w];
        v = fmaf(v, scale[r], shift[r]);
        s_t[r * W + w] = fmaxf(v, 0.f);
    }
    __syncthreads();
    for (int i = tid; i < KK * W; i += 256) {
        int k = i / W, w = i - k * W;
        float acc = b2[k];
#pragma unroll
        for (int r = 0; r < CRED; ++r)
            acc = fmaf(s_w2[k * CRED + r], s_t[r * W + w], acc);
        s_kern[k][w] = acc;
    }
    __syncthreads();
    int w = tid % W;
    int c4 = tid / W;
    float kr[KK];
#pragma unroll
    for (int k = 0; k < KK; ++k) kr[k] = s_kern[k][w];
    int cbase = z * (C / 2);
    for (int cg = cbase; cg < cbase + C / 2; cg += 4) {
        for (int i = tid; i < 4 * K * 64; i += 256) {
            int col = i & 63;
            int rc = i >> 6;
            int cc = rc / K;
            int row = rc - cc * K;
            int hh = h - 3 + row;
            int ww = col - 3;
            float v = 0.f;
            if ((unsigned)hh < H && (unsigned)ww < W)
                v = x[(((size_t)b * C + cg + cc) * H + hh) * W + ww];
            s_x[cc][row][col] = v;
        }
        __syncthreads();
        if (tid < 4 * W) {
            float acc = 0.f;
#pragma unroll
            for (int i = 0; i < K; ++i)
#pragma unroll
                for (int j = 0; j < K; ++j)
                    acc = fmaf(kr[i * K + j], s_x[c4][i][w + j], acc);
            out[(((size_t)b * C + cg + c4) * H + h) * W + w] = acc;
        }
        __syncthreads();
    }
}

extern "C" void kernel_launch(void* const* d_in, const int* in_sizes, int n_in,
                              void* d_out, int out_size, void* d_ws, size_t ws_size,
                              hipStream_t stream) {
    const float* x     = (const float*)d_in[0];
    const float* w1    = (const float*)d_in[1];
    const float* b1    = (const float*)d_in[2];
    const float* gamma = (const float*)d_in[3];
    const float* beta  = (const float*)d_in[4];
    const float* w2    = (const float*)d_in[5];
    const float* b2    = (const float*)d_in[6];
    float* out = (float*)d_out;
    float* ws  = (float*)d_ws;

    if (ws_size >= WS_NEED) {
        dim3 gA(49, B);
        kA_conv1<<<gA, 256, 0, stream>>>(x, w1, b1, ws);
        kB_bnfin<<<1, 256, 0, stream>>>(gamma, beta, ws);
        dim3 gC(H, B);
        kC_kern<<<gC, 256, 0, stream>>>(w2, b2, ws);
        dim3 gD(7 * B, 8);
        kD3_inv<<<gD, 448, 0, stream>>>(x, ws, out);
    } else {
        float* t     = ws;
        float* scale = ws + FB_SCALE_OFF;
        float* shift = ws + FB_SHIFT_OFF;
        dim3 g1((P + 255) / 256, B);
        k1_conv1<<<g1, 256, 0, stream>>>(x, w1, b1, t);
        k2_bnstats<<<CRED, 256, 0, stream>>>(t, gamma, beta, scale, shift);
        dim3 g3(H, B, 2);
        k3_involution<<<g3, 256, 0, stream>>>(x, t, scale, shift, w2, b2, out);
    }
}

// Round 12
// 46.049 us; speedup vs baseline: 1.0609x; 1.0347x over previous
//
#include <hip/hip_runtime.h>

#define C 128
#define CRED 32
#define K 7
#define KK 49
#define H 56
#define W 56
#define P (H*W)        // 3136
#define B 8
#define NPIX (B*P)     // 25088
#define BN_EPS 1e-5

// ---------------- fast-path ws layout (floats) ----------------
#define T_OFF 0
#define T_SIZE (B*CRED*P)                 // 802816
#define KERN_OFF (T_OFF + T_SIZE)
#define KERN_SIZE (B*KK*P)                // 1229312
#define NBLK_A (49*B)                     // 392
#define PSUM_OFF (KERN_OFF + KERN_SIZE)
#define PSQ_OFF (PSUM_OFF + NBLK_A*CRED)
#define SS_OFF  (PSQ_OFF + NBLK_A*CRED)
#define SCALE_OFF SS_OFF
#define SHIFT_OFF (SS_OFF + CRED)
#define WS_NEED ((size_t)(SHIFT_OFF + CRED) * sizeof(float))

// fallback layout
#define FB_SCALE_OFF T_SIZE
#define FB_SHIFT_OFF (T_SIZE + CRED)

// ============ kA v3: t = w1*x + b1 + BN partials ============
__global__ __launch_bounds__(256) void kA_conv1(const float* __restrict__ x,
                                                const float* __restrict__ w1,
                                                const float* __restrict__ b1,
                                                float* __restrict__ ws) {
    int tid = threadIdx.x;
    int bx = blockIdx.x;
    int b  = blockIdx.y;
    int px = tid & 63;
    int p  = bx * 64 + px;                       // < P (49*64 == P)
    int ru8 = __builtin_amdgcn_readfirstlane((tid >> 6) * 8);
    const float* __restrict__ wq = w1 + (size_t)ru8 * C;
    const float* xb = x + (size_t)b * C * P + p;

    float acc[8];
#pragma unroll
    for (int u = 0; u < 8; ++u) acc[u] = 0.f;
#pragma unroll 8
    for (int c = 0; c < C; ++c) {
        float xv = xb[(size_t)c * P];
#pragma unroll
        for (int u = 0; u < 8; ++u)
            acc[u] = fmaf(wq[u * C + c], xv, acc[u]);
    }
#pragma unroll
    for (int u = 0; u < 8; ++u) acc[u] += b1[ru8 + u];

    float* tb = ws + T_OFF + (size_t)b * CRED * P + p;
#pragma unroll
    for (int u = 0; u < 8; ++u)
        tb[(size_t)(ru8 + u) * P] = acc[u];

    float s[8], q[8];
#pragma unroll
    for (int u = 0; u < 8; ++u) { s[u] = acc[u]; q[u] = acc[u] * acc[u]; }
#pragma unroll
    for (int off = 32; off; off >>= 1) {
#pragma unroll
        for (int u = 0; u < 8; ++u) {
            s[u] += __shfl_xor(s[u], off);
            q[u] += __shfl_xor(q[u], off);
        }
    }
    if (px == 0) {
        int blk = b * 49 + bx;
        float* psum = ws + PSUM_OFF + (size_t)blk * CRED + ru8;
        float* psq  = ws + PSQ_OFF  + (size_t)blk * CRED + ru8;
#pragma unroll
        for (int u = 0; u < 8; ++u) { psum[u] = s[u]; psq[u] = q[u]; }
    }
}

// ============ kB: finalize BN stats ============
__global__ __launch_bounds__(256) void kB_bnfin(const float* __restrict__ gamma,
                                                const float* __restrict__ beta,
                                                float* __restrict__ ws) {
    __shared__ double sd1[8][CRED];
    __shared__ double sd2[8][CRED];
    int tid = threadIdx.x;
    int r = tid & 31, g = tid >> 5;
    double s1 = 0.0, s2 = 0.0;
    for (int i = g * 49; i < g * 49 + 49; ++i) {
        s1 += (double)ws[PSUM_OFF + i * CRED + r];
        s2 += (double)ws[PSQ_OFF + i * CRED + r];
    }
    sd1[g][r] = s1; sd2[g][r] = s2;
    __syncthreads();
    if (tid < CRED) {
        double S1 = 0.0, S2 = 0.0;
        for (int gg = 0; gg < 8; ++gg) { S1 += sd1[gg][tid]; S2 += sd2[gg][tid]; }
        double mean = S1 / NPIX;
        double var = S2 / NPIX - mean * mean;
        double sc = (double)gamma[tid] / sqrt(var + BN_EPS);
        ws[SCALE_OFF + tid] = (float)sc;
        ws[SHIFT_OFF + tid] = (float)((double)beta[tid] - mean * sc);
    }
}

// ============ kC v2: kern = b2 + w2 * relu(t*scale+shift) ============
__global__ __launch_bounds__(256) void kC_kern(const float* __restrict__ w2,
                                               const float* __restrict__ b2,
                                               float* __restrict__ ws) {
    __shared__ float s_t[CRED * W];
    __shared__ float s_w2[KK * 33];
    int tid = threadIdx.x;
    int h = blockIdx.x, b = blockIdx.y;
    for (int i = tid; i < KK * CRED; i += 256) {
        int k = i >> 5, r = i & 31;
        s_w2[k * 33 + r] = w2[i];
    }
    const float* scale = ws + SCALE_OFF;
    const float* shift = ws + SHIFT_OFF;
    for (int i = tid; i < CRED * W; i += 256) {
        int r = i / W, w = i - r * W;
        float v = ws[T_OFF + ((size_t)b * CRED + r) * P + h * W + w];
        v = fmaf(v, scale[r], shift[r]);
        s_t[r * W + w] = fmaxf(v, 0.f);
    }
    __syncthreads();
    for (int i = tid; i < KK * 14; i += 256) {
        int k = i / 14, w0 = (i - k * 14) * 4;
        float bb = b2[k];
        float a0 = bb, a1 = bb, a2 = bb, a3 = bb;
#pragma unroll
        for (int r = 0; r < CRED; ++r) {
            float4 tv = *(const float4*)&s_t[r * W + w0];
            float wv = s_w2[k * 33 + r];
            a0 = fmaf(wv, tv.x, a0);
            a1 = fmaf(wv, tv.y, a1);
            a2 = fmaf(wv, tv.z, a2);
            a3 = fmaf(wv, tv.w, a3);
        }
        float4 o = {a0, a1, a2, a3};
        *(float4*)&ws[KERN_OFF + ((size_t)b * KK + k) * P + h * W + w0] = o;
    }
}

// ============ kD4: vertical pixel-pair involution ============
// Thread owns pixels (r0,c) and (r0+1,c): their 7-row tap windows overlap in 6 rows,
// so each LDS x-read feeds BOTH pixels (2 FMAs, different kern scalars) -> LDS reads
// cut to 4/7 of kD3. NG=2 groups (8 ch/block) keeps acc at 16 floats (no spill).
// grid 512: bid%8 = b -> all blocks of a batch on one XCD (kern+x L2-resident).
// 2 blocks/CU (43.5KB LDS), 14 waves.
#define TH4 14
#define XR4 20            // TH4 + 6
#define XP4 68
#define NG4 2
__global__ __launch_bounds__(448) void kD4_inv(const float* __restrict__ x,
                                               const float* __restrict__ ws,
                                               float* __restrict__ out) {
    __shared__ float4 s_x[XR4 * NG4 * XP4];   // 20*2*68*16 = 43520 B
    int tid = threadIdx.x;
    int bid = blockIdx.x;
    int b    = bid & 7;
    int z    = (bid >> 3) & 15;
    int tile = bid >> 7;                  // 0..3
    int h0 = tile * TH4;
    int rp = tid / W;                     // 0..7 (7 = staging-only)
    int c  = tid - rp * W;                // 0..55
    bool owns = rp < 7;
    int r0 = h0 + 2 * rp;                 // first row of the pair

    int cg0 = z * (4 * NG4);              // 8 channels
    const size_t xbase = ((size_t)b * C + cg0) * P;

    // ---- stage x halo: XR4 x NG4 x 64 float4 slots ----
#pragma unroll
    for (int s = 0; s < 6; ++s) {
        int lin = tid + s * 448;
        if (lin < XR4 * NG4 * 64) {
            int row = lin >> 7;           // /(NG4*64)
            int rem = lin & 127;
            int g   = rem >> 6;
            int col = rem & 63;
            int hh = h0 - 3 + row, ww = col - 3;
            float m = ((unsigned)hh < H && (unsigned)ww < W) ? 1.f : 0.f;
            int off = (m != 0.f) ? (hh * W + ww) : 0;
            const float* xc = x + xbase + (size_t)(4 * g) * P;
            float4 f;
            f.x = xc[off] * m;          f.y = xc[P + off] * m;
            f.z = xc[2 * P + off] * m;  f.w = xc[3 * P + off] * m;
            s_x[(row * NG4 + g) * XP4 + col] = f;
        }
    }
    __syncthreads();

    int p0 = owns ? (r0 * W + c) : 0;
    const float* kp0 = ws + KERN_OFF + (size_t)b * KK * P + p0;   // pixel (r0,c)
    const float* kp1 = kp0 + W;                                    // pixel (r0+1,c)

    float4 a00 = make_float4(0,0,0,0), a01 = a00;   // px0, g0/g1
    float4 a10 = a00, a11 = a00;                    // px1, g0/g1

    const float4* xs = s_x + (2 * rp * NG4) * XP4 + c;   // staged row (r0-3)

    float kv0[7], kv1[7];
#pragma unroll 1
    for (int ri = 0; ri < 8; ++ri) {
        // kern rows: px0 uses tap-row ri (valid ri<=6); px1 uses ri-1 (valid ri>=1)
        float mk0 = (ri <= 6) ? 1.f : 0.f;
        float mk1 = (ri >= 1) ? 1.f : 0.f;
        int t0 = ((ri <= 6) ? ri : 6) * 7;
        int t1 = ((ri >= 1) ? ri - 1 : 0) * 7;
#pragma unroll
        for (int j = 0; j < 7; ++j) kv0[j] = kp0[(size_t)(t0 + j) * P] * mk0;
#pragma unroll
        for (int j = 0; j < 7; ++j) kv1[j] = kp1[(size_t)(t1 + j) * P] * mk1;

        const float4* xr = xs + ri * (NG4 * XP4);
#pragma unroll
        for (int j = 0; j < 7; ++j) {
            float4 xv0 = xr[j];            // g=0
            float4 xv1 = xr[XP4 + j];      // g=1
            float k0 = kv0[j], k1 = kv1[j];
            a00.x = fmaf(k0, xv0.x, a00.x);  a00.y = fmaf(k0, xv0.y, a00.y);
            a00.z = fmaf(k0, xv0.z, a00.z);  a00.w = fmaf(k0, xv0.w, a00.w);
            a10.x = fmaf(k1, xv0.x, a10.x);  a10.y = fmaf(k1, xv0.y, a10.y);
            a10.z = fmaf(k1, xv0.z, a10.z);  a10.w = fmaf(k1, xv0.w, a10.w);
            a01.x = fmaf(k0, xv1.x, a01.x);  a01.y = fmaf(k0, xv1.y, a01.y);
            a01.z = fmaf(k0, xv1.z, a01.z);  a01.w = fmaf(k0, xv1.w, a01.w);
            a11.x = fmaf(k1, xv1.x, a11.x);  a11.y = fmaf(k1, xv1.y, a11.y);
            a11.z = fmaf(k1, xv1.z, a11.z);  a11.w = fmaf(k1, xv1.w, a11.w);
        }
    }

    if (owns) {
        float* o0 = out + xbase + p0;          // (r0, c), channel cg0
        float* o1 = o0 + W;                    // (r0+1, c)
        o0[0] = a00.x;  o0[P] = a00.y;  o0[2*P] = a00.z;  o0[3*P] = a00.w;
        o1[0] = a10.x;  o1[P] = a10.y;  o1[2*P] = a10.z;  o1[3*P] = a10.w;
        float* o2 = o0 + 4 * P;                // g=1 channels
        float* o3 = o1 + 4 * P;
        o2[0] = a01.x;  o2[P] = a01.y;  o2[2*P] = a01.z;  o2[3*P] = a01.w;
        o3[0] = a11.x;  o3[P] = a11.y;  o3[2*P] = a11.z;  o3[3*P] = a11.w;
    }
}

// ===================== fallback (proven, needs only 3.3MB ws) =====================
__global__ __launch_bounds__(256) void k1_conv1(const float* __restrict__ x,
                                                const float* __restrict__ w1,
                                                const float* __restrict__ b1,
                                                float* __restrict__ t) {
    __shared__ float s_w1t[C * CRED];
    int tid = threadIdx.x;
    for (int i = tid; i < C * CRED; i += 256) {
        int c = i >> 5, r = i & 31;
        s_w1t[i] = w1[r * C + c];
    }
    __syncthreads();
    int b = blockIdx.y;
    int p = blockIdx.x * 256 + tid;
    if (p >= P) return;
    float acc[CRED];
#pragma unroll
    for (int r = 0; r < CRED; ++r) acc[r] = 0.f;
    const float* xb = x + (size_t)b * C * P + p;
    for (int c = 0; c < C; ++c) {
        float xv = xb[(size_t)c * P];
#pragma unroll
        for (int r = 0; r < CRED; ++r)
            acc[r] = fmaf(s_w1t[c * CRED + r], xv, acc[r]);
    }
    float* tb = t + (size_t)b * CRED * P + p;
#pragma unroll
    for (int r = 0; r < CRED; ++r)
        tb[(size_t)r * P] = acc[r] + b1[r];
}

__global__ __launch_bounds__(256) void k2_bnstats(const float* __restrict__ t,
                                                  const float* __restrict__ gamma,
                                                  const float* __restrict__ beta,
                                                  float* __restrict__ scale,
                                                  float* __restrict__ shift) {
    int r = blockIdx.x;
    int tid = threadIdx.x;
    double s = 0.0, s2 = 0.0;
    for (int i = tid; i < NPIX; i += 256) {
        int b = i / P, p = i - b * P;
        float v = t[((size_t)b * CRED + r) * P + p];
        s += v;
        s2 += (double)v * v;
    }
    __shared__ double ls[256], ls2[256];
    ls[tid] = s; ls2[tid] = s2;
    __syncthreads();
    for (int off = 128; off > 0; off >>= 1) {
        if (tid < off) { ls[tid] += ls[tid + off]; ls2[tid] += ls2[tid + off]; }
        __syncthreads();
    }
    if (tid == 0) {
        double mean = ls[0] / NPIX;
        double var = ls2[0] / NPIX - mean * mean;
        double sc = (double)gamma[r] / sqrt(var + BN_EPS);
        scale[r] = (float)sc;
        shift[r] = (float)((double)beta[r] - mean * sc);
    }
}

__global__ __launch_bounds__(256) void k3_involution(const float* __restrict__ x,
                                                     const float* __restrict__ t,
                                                     const float* __restrict__ scale,
                                                     const float* __restrict__ shift,
                                                     const float* __restrict__ w2,
                                                     const float* __restrict__ b2,
                                                     float* __restrict__ out) {
    int h = blockIdx.x;
    int b = blockIdx.y;
    int z = blockIdx.z;
    int tid = threadIdx.x;
    __shared__ float s_w2[KK * CRED];
    __shared__ float s_t[CRED * W];
    __shared__ float s_kern[KK][W];
    __shared__ float s_x[4][K][64];
    for (int i = tid; i < KK * CRED; i += 256) s_w2[i] = w2[i];
    for (int i = tid; i < CRED * W; i += 256) {
        int r = i / W, w = i - r * W;
        float v = t[((size_t)b * CRED + r) * P + h * W + w];
        v = fmaf(v, scale[r], shift[r]);
        s_t[r * W + w] = fmaxf(v, 0.f);
    }
    __syncthreads();
    for (int i = tid; i < KK * W; i += 256) {
        int k = i / W, w = i - k * W;
        float acc = b2[k];
#pragma unroll
        for (int r = 0; r < CRED; ++r)
            acc = fmaf(s_w2[k * CRED + r], s_t[r * W + w], acc);
        s_kern[k][w] = acc;
    }
    __syncthreads();
    int w = tid % W;
    int c4 = tid / W;
    float kr[KK];
#pragma unroll
    for (int k = 0; k < KK; ++k) kr[k] = s_kern[k][w];
    int cbase = z * (C / 2);
    for (int cg = cbase; cg < cbase + C / 2; cg += 4) {
        for (int i = tid; i < 4 * K * 64; i += 256) {
            int col = i & 63;
            int rc = i >> 6;
            int cc = rc / K;
            int row = rc - cc * K;
            int hh = h - 3 + row;
            int ww = col - 3;
            float v = 0.f;
            if ((unsigned)hh < H && (unsigned)ww < W)
                v = x[(((size_t)b * C + cg + cc) * H + hh) * W + ww];
            s_x[cc][row][col] = v;
        }
        __syncthreads();
        if (tid < 4 * W) {
            float acc = 0.f;
#pragma unroll
            for (int i = 0; i < K; ++i)
#pragma unroll
                for (int j = 0; j < K; ++j)
                    acc = fmaf(kr[i * K + j], s_x[c4][i][w + j], acc);
            out[(((size_t)b * C + cg + c4) * H + h) * W + w] = acc;
        }
        __syncthreads();
    }
}

extern "C" void kernel_launch(void* const* d_in, const int* in_sizes, int n_in,
                              void* d_out, int out_size, void* d_ws, size_t ws_size,
                              hipStream_t stream) {
    const float* x     = (const float*)d_in[0];
    const float* w1    = (const float*)d_in[1];
    const float* b1    = (const float*)d_in[2];
    const float* gamma = (const float*)d_in[3];
    const float* beta  = (const float*)d_in[4];
    const float* w2    = (const float*)d_in[5];
    const float* b2    = (const float*)d_in[6];
    float* out = (float*)d_out;
    float* ws  = (float*)d_ws;

    if (ws_size >= WS_NEED) {
        dim3 gA(49, B);
        kA_conv1<<<gA, 256, 0, stream>>>(x, w1, b1, ws);
        kB_bnfin<<<1, 256, 0, stream>>>(gamma, beta, ws);
        dim3 gC(H, B);
        kC_kern<<<gC, 256, 0, stream>>>(w2, b2, ws);
        kD4_inv<<<512, 448, 0, stream>>>(x, ws, out);
    } else {
        float* t     = ws;
        float* scale = ws + FB_SCALE_OFF;
        float* shift = ws + FB_SHIFT_OFF;
        dim3 g1((P + 255) / 256, B);
        k1_conv1<<<g1, 256, 0, stream>>>(x, w1, b1, t);
        k2_bnstats<<<CRED, 256, 0, stream>>>(t, gamma, beta, scale, shift);
        dim3 g3(H, B, 2);
        k3_involution<<<g3, 256, 0, stream>>>(x, t, scale, shift, w2, b2, out);
    }
}